// Round 9
// baseline (832.198 us; speedup 1.0000x reference)
//
#include <hip/hip_runtime.h>

#define Tv 128

typedef float v2 __attribute__((ext_vector_type(2)));

__device__ __forceinline__ v2 pkfma(v2 a, v2 b, v2 c) {
  return __builtin_elementwise_fma(a, b, c);
}

// ---- DPP / cross-lane helpers
template<int CTRL>
__device__ __forceinline__ float dppx(float x) {
  return __int_as_float(__builtin_amdgcn_update_dpp(0, __float_as_int(x), CTRL, 0xF, 0xF, true));
}
__device__ __forceinline__ float dpp_rm(float x, int ctrl, int rm) {
  switch (ctrl) {
    default: return 0.f;
    case 0x111: return __int_as_float(__builtin_amdgcn_update_dpp(0, __float_as_int(x), 0x111, 0xF, 0xF, true));
    case 0x112: return __int_as_float(__builtin_amdgcn_update_dpp(0, __float_as_int(x), 0x112, 0xF, 0xF, true));
    case 0x114: return __int_as_float(__builtin_amdgcn_update_dpp(0, __float_as_int(x), 0x114, 0xF, 0xF, true));
    case 0x118: return __int_as_float(__builtin_amdgcn_update_dpp(0, __float_as_int(x), 0x118, 0xF, 0xF, true));
    case 0x142: return __int_as_float(__builtin_amdgcn_update_dpp(0, __float_as_int(x), 0x142, 0xA, 0xF, true));
    case 0x143: return __int_as_float(__builtin_amdgcn_update_dpp(0, __float_as_int(x), 0x143, 0xC, 0xF, true));
  }
}
// full-wave64 sum, broadcast via readlane(63)
__device__ __forceinline__ float wave_sum(float x) {
  x += dpp_rm(x, 0x111, 0xF);
  x += dpp_rm(x, 0x112, 0xF);
  x += dpp_rm(x, 0x114, 0xF);
  x += dpp_rm(x, 0x118, 0xF);
  x += dpp_rm(x, 0x142, 0xA);
  x += dpp_rm(x, 0x143, 0xC);
  return __int_as_float(__builtin_amdgcn_readlane(__float_as_int(x), 63));
}
template<int M>
__device__ __forceinline__ float lane_xor(float x) {
  if constexpr (M == 1)       return dppx<0xB1>(x);    // quad_perm [1,0,3,2]
  else if constexpr (M == 2)  return dppx<0x4E>(x);    // quad_perm [2,3,0,1]
  else if constexpr (M == 8)  return dppx<0x128>(x);   // row_ror:8 == xor8
  else if constexpr (M == 32) return __shfl_xor(x, 32, 64);
  else return __int_as_float(__builtin_amdgcn_ds_swizzle(__float_as_int(x), (M << 10) | 0x1F));
}
// xor4 substitute, VALID ONLY when x is constant over lane bits 0,1:
// row_half_mirror (l -> l^7) == l^4 under that precondition. Pure DPP.
__device__ __forceinline__ float fold4(float x) { return dppx<0x141>(x); }
__device__ __forceinline__ float bperm(int addr, float x) {
  return __int_as_float(__builtin_amdgcn_ds_bpermute(addr, __float_as_int(x)));
}
__device__ __forceinline__ float rdlane(float x, int l) {
  return __int_as_float(__builtin_amdgcn_readlane(__float_as_int(x), l));
}
__device__ __forceinline__ float fast_rcp(float x){ return __builtin_amdgcn_rcpf(x); }
__device__ __forceinline__ float fast_rsq(float x){ return __builtin_amdgcn_rsqf(x); }
__device__ __forceinline__ float tanh_(float x){
  float e = __expf(2.0f * x);
  return 1.0f - 2.0f * fast_rcp(e + 1.0f);
}
__device__ __forceinline__ float sigm_(float x){
  return fast_rcp(1.0f + __expf(-x));
}

// State: 256 amps = 8 regs x 32 lanes, packed as v2 S[4]; s[r] = S[r>>1][r&1].
// idx = reg(3b: bits 7..5) | l5(5b: bits 4..0).
// q0 -> reg bit2; q1 -> reg bit1; q2 -> reg bit0 (x/y); q3..q7 -> lane masks 16,8,4,2,1.
template<int Q>
__device__ __forceinline__ void ry_pk(v2* S, float cc, float ss, int l5) {
  const v2 cc2 = {cc, cc};
  if constexpr (Q == 0) {
    const v2 ss2 = {ss, ss};
    #pragma unroll
    for (int k = 0; k < 2; k++) {
      v2 a0 = S[k], a1 = S[k + 2];
      S[k]     = pkfma(cc2, a0, -(ss2 * a1));
      S[k + 2] = pkfma(ss2, a0,  (cc2 * a1));
    }
  } else if constexpr (Q == 1) {
    const v2 ss2 = {ss, ss};
    #pragma unroll
    for (int k = 0; k < 4; k += 2) {
      v2 a0 = S[k], a1 = S[k + 1];
      S[k]     = pkfma(cc2, a0, -(ss2 * a1));
      S[k + 1] = pkfma(ss2, a0,  (cc2 * a1));
    }
  } else if constexpr (Q == 2) {
    const v2 nss = {-ss, ss};
    #pragma unroll
    for (int k = 0; k < 4; k++) {
      v2 a = S[k];
      v2 sw = __builtin_shufflevector(a, a, 1, 0);
      S[k] = pkfma(cc2, a, nss * sw);
    }
  } else {
    constexpr int m = 16 >> (Q - 3);
    float ssn = (l5 & m) ? ss : -ss;
    const v2 ssn2 = {ssn, ssn};
    #pragma unroll
    for (int k = 0; k < 4; k++) {
      v2 o;
      o.x = lane_xor<m>(S[k].x);
      o.y = lane_xor<m>(S[k].y);
      S[k] = pkfma(cc2, S[k], ssn2 * o);
    }
  }
}

struct __align__(16) SMem {
  float cs[4][66];    // staging only: per gate (cos,sin) at [(l*8+q)*2]
  float zbuf[32];     // z[gate][qubit]
  float embp[2][2];   // emb-LN partials (s1,s2)
  float projp[2][8];  // proj partials
  float outp[2][4];   // out-epilogue partials (init: SW/KB)
};

__global__ __launch_bounds__(128, 2) void qlstm_kernel(
    const float* __restrict__ x,     const float* __restrict__ pe,
    const float* __restrict__ emb_w, const float* __restrict__ emb_b,
    const float* __restrict__ emb_g, const float* __restrict__ emb_bt,
    const float* __restrict__ ip_w,  const float* __restrict__ ip_b,
    const float* __restrict__ in_g,  const float* __restrict__ in_b,
    const float* __restrict__ wq_i,  const float* __restrict__ wq_f,
    const float* __restrict__ wq_gt, const float* __restrict__ wq_o,
    const float* __restrict__ pi_w,  const float* __restrict__ pi_b,
    const float* __restrict__ pf_w,  const float* __restrict__ pf_b,
    const float* __restrict__ pg_w,  const float* __restrict__ pg_b,
    const float* __restrict__ po_w,  const float* __restrict__ po_b,
    const float* __restrict__ on_g,  const float* __restrict__ on_b,
    const float* __restrict__ out_w, const float* __restrict__ out_b,
    float* __restrict__ out)
{
  __shared__ SMem sm;
  const int tid = threadIdx.x;          // 0..127 = row j
  const int b   = blockIdx.x;
  const int w   = tid >> 6;             // wave 0/1
  const int L   = tid & 63;
  const int l5  = L & 31;
  const int gate = w * 2 + (L >> 5);    // 0..3 = i,f,g,o
  const int o8  = L & 7;

  // ---- stage (cos,sin) table in LDS (one-time), then pull into VGPRs
  {
    int gg = tid >> 5, rem = tid & 31;
    const float* wsel = (gg == 0) ? wq_i : (gg == 1) ? wq_f : (gg == 2) ? wq_gt : wq_o;
    float th = wsel[rem] * 0.5f;
    sm.cs[gg][rem * 2]     = __cosf(th);
    sm.cs[gg][rem * 2 + 1] = __sinf(th);
  }

  // ---- persistent per-thread weights (row j = tid)
  const int j = tid;
  v2 EW[4];
  {
    float4 a = *reinterpret_cast<const float4*>(emb_w + j * 8);
    float4 c = *reinterpret_cast<const float4*>(emb_w + j * 8 + 4);
    EW[0] = {a.x, a.y}; EW[1] = {a.z, a.w}; EW[2] = {c.x, c.y}; EW[3] = {c.z, c.w};
  }
  float ebb = emb_b[j], egg = emb_g[j], ebt = emb_bt[j];
  v2 IPW1[4], IPW2[4];
  #pragma unroll
  for (int k = 0; k < 4; k++) {
    IPW1[k] = {ip_w[(2 * k) * 256 + j],       ip_w[(2 * k + 1) * 256 + j]};
    IPW2[k] = {ip_w[(2 * k) * 256 + 128 + j], ip_w[(2 * k + 1) * 256 + 128 + j]};
  }
  v2 GW[4][4];
  #pragma unroll
  for (int gg = 0; gg < 4; gg++) {
    const float* pw = (gg == 0) ? pi_w : (gg == 1) ? pf_w : (gg == 2) ? pg_w : po_w;
    float4 a = *reinterpret_cast<const float4*>(pw + j * 8);
    float4 c = *reinterpret_cast<const float4*>(pw + j * 8 + 4);
    GW[gg][0] = {a.x, a.y}; GW[gg][1] = {a.z, a.w};
    GW[gg][2] = {c.x, c.y}; GW[gg][3] = {c.z, c.w};
  }
  float gb[4] = {pi_b[j], pf_b[j], pg_b[j], po_b[j]};
  float ong = on_g[j], onb = on_b[j], ow_ = out_w[j];
  float outb = out_b[0];
  float a_ = ong * ow_;
  // angle-path constants for lane's o8 (read once from global, no LDS)
  float ipb0 = ip_b[o8], ipb1 = in_g[o8], ipb2 = in_b[o8];

  // Composed per-layer CNOT permutation (verified R4/R6)
  const int grp = L & 32;
  int aC0, aC1;
  {
    int l1 = l5 ^ ((l5 & 16) >> 1) ^ ((l5 & 4) >> 1);
    int lb = l1 ^ ((l1 & 8) >> 1) ^ ((l1 & 2) >> 1);
    aC0 = (grp | lb) << 2;
    aC1 = (grp | (lb ^ 16)) << 2;
  }

  __syncthreads();
  // pull this lane's gate cs table into VGPRs (loop-invariant; kills 32 ds_read/step)
  v2 CS[32];
  {
    const float* csg = sm.cs[gate];
    #pragma unroll
    for (int i = 0; i < 32; i++)
      CS[i] = *reinterpret_cast<const v2*>(&csg[i * 2]);
  }

  float h = 0.f, c = 0.f;
  const float* xbase = x + (size_t)b * Tv * 8;

  // ---- pre-loop: e_0 + SW/KB partials, single barrier
  float e;
  {
    float4 a = *reinterpret_cast<const float4*>(xbase);
    float4 cq = *reinterpret_cast<const float4*>(xbase + 4);
    v2 XT[4] = {{a.x,a.y},{a.z,a.w},{cq.x,cq.y},{cq.z,cq.w}};
    v2 acc = XT[0] * EW[0];
    acc = pkfma(XT[1], EW[1], acc);
    acc = pkfma(XT[2], EW[2], acc);
    acc = pkfma(XT[3], EW[3], acc);
    float er = ebb + acc.x + acc.y;
    float s1 = wave_sum(er), s2 = wave_sum(er * er);
    float r0 = wave_sum(a_), r1 = wave_sum(onb * ow_);
    if (L == 0) {
      sm.embp[w][0] = s1; sm.embp[w][1] = s2;
      sm.outp[w][0] = r0; sm.outp[w][1] = r1;
    }
    __syncthreads();
    s1 = sm.embp[0][0] + sm.embp[1][0];
    s2 = sm.embp[0][1] + sm.embp[1][1];
    float mn = s1 * 0.0078125f;
    float vr = fmaf(s2, 0.0078125f, -mn * mn);
    float inv = fast_rsq(vr + 1e-5f);
    e = (er - mn) * inv * egg + ebt + pe[j];
  }
  const float SW = sm.outp[0][0] + sm.outp[1][0];
  const float KB = sm.outp[0][1] + sm.outp[1][1] + outb;

  #pragma unroll 1
  for (int t = 0; t < Tv; t++) {
    // ---- prefetch next x,pe
    v2 XN[4]; float pen;
    {
      int tn = (t + 1) & (Tv - 1);
      float4 a = *reinterpret_cast<const float4*>(xbase + tn * 8);
      float4 cq = *reinterpret_cast<const float4*>(xbase + tn * 8 + 4);
      XN[0] = {a.x,a.y}; XN[1] = {a.z,a.w}; XN[2] = {cq.x,cq.y}; XN[3] = {cq.z,cq.w};
      pen = pe[tn * 128 + j];
    }

    // ---- proj: p_o = e*ipw1[o] + h*ipw2[o] (packed), butterfly transpose-reduce
    const v2 e2 = {e, e}, h2 = {h, h};
    v2 P2[4];
    #pragma unroll
    for (int k = 0; k < 4; k++)
      P2[k] = pkfma(e2, IPW1[k], h2 * IPW2[k]);
    const int bb0 = L & 1, bb1 = L & 2, bb2 = L & 4;
    float q_[4];
    #pragma unroll
    for (int k = 0; k < 4; k++) {
      float keep = bb0 ? P2[k].y : P2[k].x;
      float send = bb0 ? P2[k].x : P2[k].y;
      q_[k] = keep + lane_xor<1>(send);
    }
    float r_[2];
    #pragma unroll
    for (int k = 0; k < 2; k++) {
      float keep = bb1 ? q_[2 * k + 1] : q_[2 * k];
      float send = bb1 ? q_[2 * k]     : q_[2 * k + 1];
      r_[k] = keep + lane_xor<2>(send);
    }
    float u;
    {
      float keep = bb2 ? r_[1] : r_[0];
      float send = bb2 ? r_[0] : r_[1];
      u = keep + lane_xor<4>(send);
    }
    u += lane_xor<8>(u); u += lane_xor<16>(u); u += lane_xor<32>(u);
    if (L < 8) sm.projp[w][L] = u;
    __syncthreads();                                  // ===== barrier 1
    u += sm.projp[1 - w][o8];
    if (t && tid == 0) {                              // emit out[t-1] (pipelined)
      float sy  = sm.outp[0][0] + sm.outp[1][0];
      float sy2 = sm.outp[0][1] + sm.outp[1][1];
      float sya = sm.outp[0][2] + sm.outp[1][2];
      float mn2 = sy * 0.0078125f;
      float vr2 = fmaf(sy2, 0.0078125f, -mn2 * mn2);
      float inv2 = fast_rsq(vr2 + 1e-5f);
      out[b * Tv + t - 1] = fmaf(inv2, sya - mn2 * SW, KB);
    }

    // ---- angles: tanh + LN(8), all-DPP (m1, m2, fold4) -> factors via readlane
    float tv = tanh_(u + ipb0);
    float m1 = tv, m2 = tv * tv;
    m1 += lane_xor<1>(m1); m2 += lane_xor<1>(m2);
    m1 += lane_xor<2>(m1); m2 += lane_xor<2>(m2);
    m1 += fold4(m1);       m2 += fold4(m2);
    float pm = m1 * 0.125f;
    float pv = fmaf(m2, 0.125f, -pm * pm);
    float theta = (tv - pm) * fast_rsq(pv + 1e-5f) * ipb1 + ipb2;
    float ph = theta * 0.5f;
    float cE = __cosf(ph), sE = __sinf(ph);
    float fm = cE - sE, fp = cE + sE;
    float f_[16];
    #pragma unroll
    for (int qq = 0; qq < 8; qq++) {
      f_[2 * qq]     = rdlane(fm, qq);
      f_[2 * qq + 1] = rdlane(fp, qq);
    }

    // ---- VQC encode (packed)
    v2 S[4];
    {
      float g01_[4];
      #pragma unroll
      for (int i = 0; i < 4; i++)
        g01_[i] = f_[(i >> 1) & 1] * f_[2 + (i & 1)];
      float lf = f_[6 + ((l5 >> 4) & 1)] * f_[8 + ((l5 >> 3) & 1)]
               * f_[10 + ((l5 >> 2) & 1)] * f_[12 + ((l5 >> 1) & 1)]
               * f_[14 + (l5 & 1)];
      lf *= 0.0625f;
      const v2 F45 = {f_[4], f_[5]};
      #pragma unroll
      for (int k = 0; k < 4; k++) {
        float tk = lf * g01_[k];
        v2 tk2 = {tk, tk};
        S[k] = tk2 * F45;
      }
    }

    // ---- 4 variational layers: one composed bpermute + 8 packed RYs (cs from VGPR)
    #pragma unroll
    for (int l = 0; l < 4; l++) {
      v2 N0, N1, N2, N3;
      N0.x = bperm(aC0, S[0].x); N0.y = bperm(aC1, S[0].y);
      N1.x = bperm(aC1, S[1].y); N1.y = bperm(aC0, S[1].x);
      N2.x = bperm(aC0, S[3].x); N2.y = bperm(aC1, S[3].y);
      N3.x = bperm(aC1, S[2].y); N3.y = bperm(aC0, S[2].x);
      S[0] = N0; S[1] = N1; S[2] = N2; S[3] = N3;
      #define RYL(Q) { v2 cs2 = CS[l * 8 + Q]; ry_pk<Q>(S, cs2.x, cs2.y, l5); }
      RYL(0) RYL(1) RYL(2) RYL(3) RYL(4) RYL(5) RYL(6) RYL(7)
      #undef RYL
    }

    // ---- measure z_q: DPP trunk + peels; one final m16 swizzle burst (R8-verified)
    v2 P[4];
    #pragma unroll
    for (int k = 0; k < 4; k++) P[k] = S[k] * S[k];
    v2 A = P[0] + P[2];
    v2 B = P[1] + P[3];
    v2 D = (P[0] - P[2]) + (P[1] - P[3]);
    float z0 = D.x + D.y;
    v2 Ev = A - B;
    float z1 = Ev.x + Ev.y;
    v2 G = A + B;
    float z2 = G.x - G.y;
    float S_ = G.x + G.y;
    z0 += lane_xor<1>(z0); z1 += lane_xor<1>(z1); z2 += lane_xor<1>(z2);
    z0 += lane_xor<2>(z0); z1 += lane_xor<2>(z1); z2 += lane_xor<2>(z2);
    z0 += fold4(z0);       z1 += fold4(z1);       z2 += fold4(z2);
    z0 += lane_xor<8>(z0); z1 += lane_xor<8>(z1); z2 += lane_xor<8>(z2);
    float v1 = lane_xor<1>(S_);
    float S1 = S_ + v1;
    float d1 = S_ - v1;
    float z7 = (l5 & 1) ? -d1 : d1;
    z7 += lane_xor<2>(z7); z7 += fold4(z7); z7 += lane_xor<8>(z7);
    float v2s = lane_xor<2>(S1);
    float S12 = S1 + v2s;
    float d2 = S1 - v2s;
    float z6 = (l5 & 2) ? -d2 : d2;
    z6 += fold4(z6); z6 += lane_xor<8>(z6);
    float v4 = fold4(S12);
    float S124 = S12 + v4;
    float d4 = S12 - v4;
    float z5 = (l5 & 4) ? -d4 : d4;
    z5 += lane_xor<8>(z5);
    float v8 = lane_xor<8>(S124);
    float S1248 = S124 + v8;
    float d8 = S124 - v8;
    float z4 = (l5 & 8) ? -d8 : d8;
    z0 += lane_xor<16>(z0);
    z1 += lane_xor<16>(z1);
    z2 += lane_xor<16>(z2);
    z4 += lane_xor<16>(z4);
    z5 += lane_xor<16>(z5);
    z6 += lane_xor<16>(z6);
    z7 += lane_xor<16>(z7);
    float v16 = lane_xor<16>(S1248);
    float d16 = S1248 - v16;
    float z3 = (l5 & 16) ? -d16 : d16;

    if (l5 < 8) {
      float zv = z0;
      zv = (l5 == 1) ? z1 : zv;
      zv = (l5 == 2) ? z2 : zv;
      zv = (l5 == 3) ? z3 : zv;
      zv = (l5 == 4) ? z4 : zv;
      zv = (l5 == 5) ? z5 : zv;
      zv = (l5 == 6) ? z6 : zv;
      zv = (l5 == 7) ? z7 : zv;
      sm.zbuf[gate * 8 + l5] = zv;
    }

    // ---- next-step emb partials (recurrence-independent; rides barrier 2)
    v2 acc = XN[0] * EW[0];
    acc = pkfma(XN[1], EW[1], acc);
    acc = pkfma(XN[2], EW[2], acc);
    acc = pkfma(XN[3], EW[3], acc);
    float en_raw = ebb + acc.x + acc.y;
    {
      float s1n = wave_sum(en_raw), s2n = wave_sum(en_raw * en_raw);
      if (L == 0) { sm.embp[w][0] = s1n; sm.embp[w][1] = s2n; }
    }
    __syncthreads();                                  // ===== barrier 2

    // ---- gate projections + LSTM cell (packed dot products)
    float acg[4];
    #pragma unroll
    for (int gg = 0; gg < 4; gg++) {
      float4 za0 = *reinterpret_cast<float4*>(&sm.zbuf[gg * 8]);
      float4 za1 = *reinterpret_cast<float4*>(&sm.zbuf[gg * 8 + 4]);
      v2 Z0 = {za0.x, za0.y}, Z1 = {za0.z, za0.w};
      v2 Z2 = {za1.x, za1.y}, Z3 = {za1.z, za1.w};
      v2 av = Z0 * GW[gg][0];
      av = pkfma(Z1, GW[gg][1], av);
      av = pkfma(Z2, GW[gg][2], av);
      av = pkfma(Z3, GW[gg][3], av);
      acg[gg] = gb[gg] + av.x + av.y;
    }
    float it = sigm_(acg[0]), ft = sigm_(acg[1]), gt = tanh_(acg[2]), ot = sigm_(acg[3]);
    c = ft * c + it * gt;
    h = ot * tanh_(c);

    // ---- normalize e_{t+1}
    float en;
    {
      float s1 = sm.embp[0][0] + sm.embp[1][0];
      float s2 = sm.embp[0][1] + sm.embp[1][1];
      float mn = s1 * 0.0078125f;
      float vr = fmaf(s2, 0.0078125f, -mn * mn);
      float inv = fast_rsq(vr + 1e-5f);
      en = (en_raw - mn) * inv * egg + ebt + pen;
    }

    // ---- epilogue partials for step t (consumed at next barrier 1)
    {
      float y = h + e;
      float ry0 = wave_sum(y), ry1 = wave_sum(y * y), ry2 = wave_sum(y * a_);
      if (L == 0) { sm.outp[w][0] = ry0; sm.outp[w][1] = ry1; sm.outp[w][2] = ry2; }
    }
    e = en;
  }

  __syncthreads();
  if (tid == 0) {
    float sy  = sm.outp[0][0] + sm.outp[1][0];
    float sy2 = sm.outp[0][1] + sm.outp[1][1];
    float sya = sm.outp[0][2] + sm.outp[1][2];
    float mn2 = sy * 0.0078125f;
    float vr2 = fmaf(sy2, 0.0078125f, -mn2 * mn2);
    float inv2 = fast_rsq(vr2 + 1e-5f);
    out[b * Tv + Tv - 1] = fmaf(inv2, sya - mn2 * SW, KB);
  }
}

extern "C" void kernel_launch(void* const* d_in, const int* in_sizes, int n_in,
                              void* d_out, int out_size, void* d_ws, size_t ws_size,
                              hipStream_t stream) {
  qlstm_kernel<<<dim3(1024), dim3(128), 0, stream>>>(
      (const float*)d_in[0],  (const float*)d_in[1],  (const float*)d_in[2],  (const float*)d_in[3],
      (const float*)d_in[4],  (const float*)d_in[5],  (const float*)d_in[6],  (const float*)d_in[7],
      (const float*)d_in[8],  (const float*)d_in[9],  (const float*)d_in[10], (const float*)d_in[11],
      (const float*)d_in[12], (const float*)d_in[13], (const float*)d_in[14], (const float*)d_in[15],
      (const float*)d_in[16], (const float*)d_in[17], (const float*)d_in[18], (const float*)d_in[19],
      (const float*)d_in[20], (const float*)d_in[21], (const float*)d_in[22], (const float*)d_in[23],
      (const float*)d_in[24], (const float*)d_in[25],
      (float*)d_out);
}

// Round 10
// 673.918 us; speedup vs baseline: 1.2349x; 1.2349x over previous
//
#include <hip/hip_runtime.h>

#define Tv 128

typedef float v2 __attribute__((ext_vector_type(2)));

__device__ __forceinline__ v2 pkfma(v2 a, v2 b, v2 c) {
  return __builtin_elementwise_fma(a, b, c);
}

// ---- DPP / cross-lane helpers
template<int CTRL>
__device__ __forceinline__ float dppx(float x) {
  return __int_as_float(__builtin_amdgcn_update_dpp(0, __float_as_int(x), CTRL, 0xF, 0xF, true));
}
__device__ __forceinline__ float dpp_rm(float x, int ctrl, int rm) {
  switch (ctrl) {
    default: return 0.f;
    case 0x111: return __int_as_float(__builtin_amdgcn_update_dpp(0, __float_as_int(x), 0x111, 0xF, 0xF, true));
    case 0x112: return __int_as_float(__builtin_amdgcn_update_dpp(0, __float_as_int(x), 0x112, 0xF, 0xF, true));
    case 0x114: return __int_as_float(__builtin_amdgcn_update_dpp(0, __float_as_int(x), 0x114, 0xF, 0xF, true));
    case 0x118: return __int_as_float(__builtin_amdgcn_update_dpp(0, __float_as_int(x), 0x118, 0xF, 0xF, true));
    case 0x142: return __int_as_float(__builtin_amdgcn_update_dpp(0, __float_as_int(x), 0x142, 0xA, 0xF, true));
    case 0x143: return __int_as_float(__builtin_amdgcn_update_dpp(0, __float_as_int(x), 0x143, 0xC, 0xF, true));
  }
}
// full-wave64 sum, broadcast via readlane(63)
__device__ __forceinline__ float wave_sum(float x) {
  x += dpp_rm(x, 0x111, 0xF);
  x += dpp_rm(x, 0x112, 0xF);
  x += dpp_rm(x, 0x114, 0xF);
  x += dpp_rm(x, 0x118, 0xF);
  x += dpp_rm(x, 0x142, 0xA);
  x += dpp_rm(x, 0x143, 0xC);
  return __int_as_float(__builtin_amdgcn_readlane(__float_as_int(x), 63));
}
template<int M>
__device__ __forceinline__ float lane_xor(float x) {
  if constexpr (M == 1)       return dppx<0xB1>(x);    // quad_perm [1,0,3,2]
  else if constexpr (M == 2)  return dppx<0x4E>(x);    // quad_perm [2,3,0,1]
  else if constexpr (M == 8)  return dppx<0x128>(x);   // row_ror:8 == xor8 in 16-row
  else if constexpr (M == 32) return __shfl_xor(x, 32, 64);
  else return __int_as_float(__builtin_amdgcn_ds_swizzle(__float_as_int(x), (M << 10) | 0x1F));
}
// xor4 substitute, VALID ONLY when x is constant over lane bits 0,1 (row_half_mirror l^7)
__device__ __forceinline__ float fold4(float x) { return dppx<0x141>(x); }
__device__ __forceinline__ float bperm(int addr, float x) {
  return __int_as_float(__builtin_amdgcn_ds_bpermute(addr, __float_as_int(x)));
}
__device__ __forceinline__ float rdlane(float x, int l) {
  return __int_as_float(__builtin_amdgcn_readlane(__float_as_int(x), l));
}
__device__ __forceinline__ float fast_rcp(float x){ return __builtin_amdgcn_rcpf(x); }
__device__ __forceinline__ float fast_rsq(float x){ return __builtin_amdgcn_rsqf(x); }
__device__ __forceinline__ float tanh_(float x){
  float e = __expf(2.0f * x);
  return 1.0f - 2.0f * fast_rcp(e + 1.0f);
}
__device__ __forceinline__ float sigm_(float x){
  return fast_rcp(1.0f + __expf(-x));
}

// State: 256 amps = 16 regs x 16 lanes (4 gates across the 64-lane wave), packed v2 S[8].
// idx bits: b7 b6 b5 (reg k) | b4 (slot x/y) | b3..b0 (lane4). Qubit q <-> bit (7-q):
// q0->b7 (S[k]<->S[k+4]); q1->b6 (k<->k+2); q2->b5 (k<->k+1); q3->b4 (x/y);
// q4..q7 -> lane masks 8,4,2,1 (8,2,1 = DPP; 4 = ds_swizzle).
template<int Q>
__device__ __forceinline__ void ry16(v2* S, float cc, float ss, int l4) {
  const v2 cc2 = {cc, cc};
  if constexpr (Q == 0) {
    const v2 ss2 = {ss, ss};
    #pragma unroll
    for (int k = 0; k < 4; k++) {
      v2 a0 = S[k], a1 = S[k + 4];
      S[k]     = pkfma(cc2, a0, -(ss2 * a1));
      S[k + 4] = pkfma(ss2, a0,  (cc2 * a1));
    }
  } else if constexpr (Q == 1) {
    const v2 ss2 = {ss, ss};
    #pragma unroll
    for (int k0 = 0; k0 < 8; k0 += 4)
      #pragma unroll
      for (int k = k0; k < k0 + 2; k++) {
        v2 a0 = S[k], a1 = S[k + 2];
        S[k]     = pkfma(cc2, a0, -(ss2 * a1));
        S[k + 2] = pkfma(ss2, a0,  (cc2 * a1));
      }
  } else if constexpr (Q == 2) {
    const v2 ss2 = {ss, ss};
    #pragma unroll
    for (int k = 0; k < 8; k += 2) {
      v2 a0 = S[k], a1 = S[k + 1];
      S[k]     = pkfma(cc2, a0, -(ss2 * a1));
      S[k + 1] = pkfma(ss2, a0,  (cc2 * a1));
    }
  } else if constexpr (Q == 3) {
    const v2 nss = {-ss, ss};
    #pragma unroll
    for (int k = 0; k < 8; k++) {
      v2 a = S[k];
      v2 sw = __builtin_shufflevector(a, a, 1, 0);
      S[k] = pkfma(cc2, a, nss * sw);
    }
  } else {
    constexpr int m = 8 >> (Q - 4);   // Q4->8, Q5->4, Q6->2, Q7->1
    float ssn = (l4 & m) ? ss : -ss;
    const v2 ssn2 = {ssn, ssn};
    #pragma unroll
    for (int k = 0; k < 8; k++) {
      v2 o;
      o.x = lane_xor<m>(S[k].x);
      o.y = lane_xor<m>(S[k].y);
      S[k] = pkfma(cc2, S[k], ssn2 * o);
    }
  }
}

__global__ __launch_bounds__(64, 1) void qlstm_kernel(
    const float* __restrict__ x,     const float* __restrict__ pe,
    const float* __restrict__ emb_w, const float* __restrict__ emb_b,
    const float* __restrict__ emb_g, const float* __restrict__ emb_bt,
    const float* __restrict__ ip_w,  const float* __restrict__ ip_b,
    const float* __restrict__ in_g,  const float* __restrict__ in_b,
    const float* __restrict__ wq_i,  const float* __restrict__ wq_f,
    const float* __restrict__ wq_gt, const float* __restrict__ wq_o,
    const float* __restrict__ pi_w,  const float* __restrict__ pi_b,
    const float* __restrict__ pf_w,  const float* __restrict__ pf_b,
    const float* __restrict__ pg_w,  const float* __restrict__ pg_b,
    const float* __restrict__ po_w,  const float* __restrict__ po_b,
    const float* __restrict__ on_g,  const float* __restrict__ on_b,
    const float* __restrict__ out_w, const float* __restrict__ out_b,
    float* __restrict__ out)
{
  __shared__ float cs[4][68];   // per gate, per layer: 16 floats (8 x (cos,sin)), 16B-aligned rows
  const int L   = threadIdx.x;  // 0..63
  const int b   = blockIdx.x;
  const int l4  = L & 15;
  const int gate = L >> 4;
  const int o8  = L & 7;

  // ---- stage (cos,sin) table: entry (gg, layer l, qubit q) at cs[gg][l*16 + 2q]
  #pragma unroll
  for (int half = 0; half < 2; half++) {
    int e = L + half * 64;          // 0..127
    int gg = e >> 5, rem = e & 31;  // rem = l*8+q
    const float* wsel = (gg == 0) ? wq_i : (gg == 1) ? wq_f : (gg == 2) ? wq_gt : wq_o;
    float th = wsel[rem] * 0.5f;
    cs[gg][(rem >> 3) * 16 + (rem & 7) * 2]     = __cosf(th);
    cs[gg][(rem >> 3) * 16 + (rem & 7) * 2 + 1] = __sinf(th);
  }
  __syncthreads();   // once, outside the t-loop

  // ---- per-lane rows j0 = L, j1 = L+64
  const int j0 = L, j1 = L + 64;
  v2 EW0[4], EW1[4];
  {
    float4 a = *reinterpret_cast<const float4*>(emb_w + j0 * 8);
    float4 c = *reinterpret_cast<const float4*>(emb_w + j0 * 8 + 4);
    EW0[0] = {a.x,a.y}; EW0[1] = {a.z,a.w}; EW0[2] = {c.x,c.y}; EW0[3] = {c.z,c.w};
    float4 d = *reinterpret_cast<const float4*>(emb_w + j1 * 8);
    float4 f = *reinterpret_cast<const float4*>(emb_w + j1 * 8 + 4);
    EW1[0] = {d.x,d.y}; EW1[1] = {d.z,d.w}; EW1[2] = {f.x,f.y}; EW1[3] = {f.z,f.w};
  }
  float ebb0 = emb_b[j0], egg0 = emb_g[j0], ebt0 = emb_bt[j0];
  float ebb1 = emb_b[j1], egg1 = emb_g[j1], ebt1 = emb_bt[j1];
  v2 IPW1a[4], IPW2a[4], IPW1b[4], IPW2b[4];
  #pragma unroll
  for (int k = 0; k < 4; k++) {
    IPW1a[k] = {ip_w[(2*k)*256 + j0],       ip_w[(2*k+1)*256 + j0]};
    IPW2a[k] = {ip_w[(2*k)*256 + 128 + j0], ip_w[(2*k+1)*256 + 128 + j0]};
    IPW1b[k] = {ip_w[(2*k)*256 + j1],       ip_w[(2*k+1)*256 + j1]};
    IPW2b[k] = {ip_w[(2*k)*256 + 128 + j1], ip_w[(2*k+1)*256 + 128 + j1]};
  }
  float gwa[4][8], gwb[4][8], gba[4], gbb[4];
  #pragma unroll
  for (int gg = 0; gg < 4; gg++) {
    const float* pw = (gg == 0) ? pi_w : (gg == 1) ? pf_w : (gg == 2) ? pg_w : po_w;
    const float* pb = (gg == 0) ? pi_b : (gg == 1) ? pf_b : (gg == 2) ? pg_b : po_b;
    float4 a = *reinterpret_cast<const float4*>(pw + j0 * 8);
    float4 c = *reinterpret_cast<const float4*>(pw + j0 * 8 + 4);
    gwa[gg][0]=a.x; gwa[gg][1]=a.y; gwa[gg][2]=a.z; gwa[gg][3]=a.w;
    gwa[gg][4]=c.x; gwa[gg][5]=c.y; gwa[gg][6]=c.z; gwa[gg][7]=c.w;
    float4 d = *reinterpret_cast<const float4*>(pw + j1 * 8);
    float4 f = *reinterpret_cast<const float4*>(pw + j1 * 8 + 4);
    gwb[gg][0]=d.x; gwb[gg][1]=d.y; gwb[gg][2]=d.z; gwb[gg][3]=d.w;
    gwb[gg][4]=f.x; gwb[gg][5]=f.y; gwb[gg][6]=f.z; gwb[gg][7]=f.w;
    gba[gg] = pb[j0]; gbb[gg] = pb[j1];
  }
  float a0_ = on_g[j0] * out_w[j0], a1_ = on_g[j1] * out_w[j1];
  float bw0 = on_b[j0] * out_w[j0], bw1 = on_b[j1] * out_w[j1];
  float ipb0 = ip_b[o8], ing = in_g[o8], inb = in_b[o8];

  // ---- composed-CNOT bpermute addresses (one round per layer)
  // src lane = lx(l) for dest slot x; lx(l)^12 for dest slot y (derived & spot-checked):
  // lx = l ^ (b3?4:0) ^ (b2?2:0) ^ ((b1^b2)?1:0)
  const int grp = L & 48;
  int aX, aY;
  {
    int lx = l4 ^ ((l4 & 8) ? 4 : 0) ^ ((l4 & 4) ? 2 : 0) ^ ((((l4 >> 1) ^ (l4 >> 2)) & 1) ? 1 : 0);
    aX = (grp | lx) << 2;
    aY = aX ^ 48;   // lane ^ 12
  }

  const float* xbase = x + (size_t)b * Tv * 8;
  float h0 = 0.f, h1 = 0.f, c0 = 0.f, c1 = 0.f;

  // ---- priming: e_0 rows + SW/KB (all in-wave, no LDS)
  float e0, e1;
  const float SW = wave_sum(a0_ + a1_);
  const float KB = wave_sum(bw0 + bw1) + out_b[0];
  {
    float4 a = *reinterpret_cast<const float4*>(xbase);
    float4 cq = *reinterpret_cast<const float4*>(xbase + 4);
    v2 XT[4] = {{a.x,a.y},{a.z,a.w},{cq.x,cq.y},{cq.z,cq.w}};
    v2 ac0 = XT[0]*EW0[0]; ac0 = pkfma(XT[1],EW0[1],ac0); ac0 = pkfma(XT[2],EW0[2],ac0); ac0 = pkfma(XT[3],EW0[3],ac0);
    v2 ac1 = XT[0]*EW1[0]; ac1 = pkfma(XT[1],EW1[1],ac1); ac1 = pkfma(XT[2],EW1[2],ac1); ac1 = pkfma(XT[3],EW1[3],ac1);
    float er0 = ebb0 + ac0.x + ac0.y;
    float er1 = ebb1 + ac1.x + ac1.y;
    float s1 = wave_sum(er0 + er1);
    float s2 = wave_sum(er0*er0 + er1*er1);
    float mn = s1 * 0.0078125f;
    float vr = fmaf(s2, 0.0078125f, -mn * mn);
    float inv = fast_rsq(vr + 1e-5f);
    e0 = (er0 - mn) * inv * egg0 + ebt0 + pe[j0];
    e1 = (er1 - mn) * inv * egg1 + ebt1 + pe[j1];
  }

  #pragma unroll 1
  for (int t = 0; t < Tv; t++) {
    // ---- prefetch next x, pe
    v2 XN[4]; float pen0, pen1;
    {
      int tn = (t + 1) & (Tv - 1);
      float4 a = *reinterpret_cast<const float4*>(xbase + tn * 8);
      float4 cq = *reinterpret_cast<const float4*>(xbase + tn * 8 + 4);
      XN[0] = {a.x,a.y}; XN[1] = {a.z,a.w}; XN[2] = {cq.x,cq.y}; XN[3] = {cq.z,cq.w};
      pen0 = pe[tn * 128 + j0];
      pen1 = pe[tn * 128 + j1];
    }

    // ---- proj: both rows accumulated, butterfly over full wave (no LDS, no barrier)
    const v2 e20 = {e0,e0}, h20 = {h0,h0}, e21 = {e1,e1}, h21 = {h1,h1};
    v2 P2[4];
    #pragma unroll
    for (int k = 0; k < 4; k++) {
      v2 acc = e20 * IPW1a[k];
      acc = pkfma(h20, IPW2a[k], acc);
      acc = pkfma(e21, IPW1b[k], acc);
      P2[k] = pkfma(h21, IPW2b[k], acc);
    }
    const int bb0 = L & 1, bb1 = L & 2, bb2 = L & 4;
    float q_[4];
    #pragma unroll
    for (int k = 0; k < 4; k++) {
      float keep = bb0 ? P2[k].y : P2[k].x;
      float send = bb0 ? P2[k].x : P2[k].y;
      q_[k] = keep + lane_xor<1>(send);
    }
    float r_[2];
    #pragma unroll
    for (int k = 0; k < 2; k++) {
      float keep = bb1 ? q_[2*k+1] : q_[2*k];
      float send = bb1 ? q_[2*k]   : q_[2*k+1];
      r_[k] = keep + lane_xor<2>(send);
    }
    float u;
    {
      float keep = bb2 ? r_[1] : r_[0];
      float send = bb2 ? r_[0] : r_[1];
      u = keep + lane_xor<4>(send);
    }
    u += lane_xor<8>(u); u += lane_xor<16>(u); u += lane_xor<32>(u);

    // ---- angles: tanh + LN(8) all-DPP; encode factors via readlane
    float tv = tanh_(u + ipb0);
    float m1 = tv, m2 = tv * tv;
    m1 += lane_xor<1>(m1); m2 += lane_xor<1>(m2);
    m1 += lane_xor<2>(m1); m2 += lane_xor<2>(m2);
    m1 += fold4(m1);       m2 += fold4(m2);
    float pm = m1 * 0.125f;
    float pv = fmaf(m2, 0.125f, -pm * pm);
    float theta = (tv - pm) * fast_rsq(pv + 1e-5f) * ing + inb;
    float ph = theta * 0.5f;
    float cE = __cosf(ph), sE = __sinf(ph);
    float fm = cE - sE, fp = cE + sE;
    float f_[16];
    #pragma unroll
    for (int qq = 0; qq < 8; qq++) {
      f_[2*qq]     = rdlane(fm, qq);
      f_[2*qq + 1] = rdlane(fp, qq);
    }

    // ---- encode: S[k] (k = q0q1q2 bits), slot = q3, lanes = q4..q7
    v2 S[8];
    {
      float lf = f_[8 + ((l4 >> 3) & 1)] * f_[10 + ((l4 >> 2) & 1)]
               * f_[12 + ((l4 >> 1) & 1)] * f_[14 + (l4 & 1)];
      lf *= 0.0625f;
      const v2 F67 = {f_[6], f_[7]};
      #pragma unroll
      for (int k = 0; k < 8; k++) {
        float tk = lf * f_[(k >> 2) & 1] * f_[2 + ((k >> 1) & 1)] * f_[4 + (k & 1)];
        v2 tk2 = {tk, tk};
        S[k] = tk2 * F67;
      }
    }

    // ---- 4 variational layers: ONE composed bpermute round + 8 RYs
    #pragma unroll
    for (int l = 0; l < 4; l++) {
      const float* cb = &cs[gate][l * 16];
      float4 cA = *reinterpret_cast<const float4*>(cb);
      float4 cB = *reinterpret_cast<const float4*>(cb + 4);
      float4 cC = *reinterpret_cast<const float4*>(cb + 8);
      float4 cD = *reinterpret_cast<const float4*>(cb + 12);
      v2 N[8];
      N[0].x = bperm(aX, S[0].x); N[0].y = bperm(aY, S[0].y);
      N[1].x = bperm(aX, S[1].y); N[1].y = bperm(aY, S[1].x);
      N[2].x = bperm(aX, S[3].y); N[2].y = bperm(aY, S[3].x);
      N[3].x = bperm(aX, S[2].x); N[3].y = bperm(aY, S[2].y);
      N[4].x = bperm(aX, S[6].x); N[4].y = bperm(aY, S[6].y);
      N[5].x = bperm(aX, S[7].y); N[5].y = bperm(aY, S[7].x);
      N[6].x = bperm(aX, S[5].y); N[6].y = bperm(aY, S[5].x);
      N[7].x = bperm(aX, S[4].x); N[7].y = bperm(aY, S[4].y);
      #pragma unroll
      for (int k = 0; k < 8; k++) S[k] = N[k];
      ry16<0>(S, cA.x, cA.y, l4);
      ry16<1>(S, cA.z, cA.w, l4);
      ry16<2>(S, cB.x, cB.y, l4);
      ry16<3>(S, cB.z, cB.w, l4);
      ry16<4>(S, cC.x, cC.y, l4);
      ry16<5>(S, cC.z, cC.w, l4);
      ry16<6>(S, cD.x, cD.y, l4);
      ry16<7>(S, cD.z, cD.w, l4);
    }

    // ---- measure: reg-qubit combos + all-DPP lane trees (zero DS)
    v2 P[8];
    #pragma unroll
    for (int k = 0; k < 8; k++) P[k] = S[k] * S[k];
    v2 Q01 = P[0] + P[1], Q23 = P[2] + P[3], Q45 = P[4] + P[5], Q67 = P[6] + P[7];
    v2 Slo = Q01 + Q23, Shi = Q45 + Q67;
    float z0 = (Slo.x + Slo.y) - (Shi.x + Shi.y);
    v2 T1p = Q01 + Q45, T1m = Q23 + Q67;
    float z1 = (T1p.x + T1p.y) - (T1m.x + T1m.y);
    v2 T2p = (P[0] + P[2]) + (P[4] + P[6]);
    v2 T2m = (P[1] + P[3]) + (P[5] + P[7]);
    float z2 = (T2p.x + T2p.y) - (T2m.x + T2m.y);
    v2 G = Slo + Shi;
    float z3 = G.x - G.y;
    float S_ = G.x + G.y;
    // reg-qubit z folds over 16-lane group: m1,m2,fold4,m8 (all DPP)
    z0 += lane_xor<1>(z0); z1 += lane_xor<1>(z1); z2 += lane_xor<1>(z2); z3 += lane_xor<1>(z3);
    z0 += lane_xor<2>(z0); z1 += lane_xor<2>(z1); z2 += lane_xor<2>(z2); z3 += lane_xor<2>(z3);
    z0 += fold4(z0);       z1 += fold4(z1);       z2 += fold4(z2);       z3 += fold4(z3);
    z0 += lane_xor<8>(z0); z1 += lane_xor<8>(z1); z2 += lane_xor<8>(z2); z3 += lane_xor<8>(z3);
    // lane-qubit trunk/peel: q7(m1), q6(m2), q5(m4 via fold4), q4(m8) — all DPP
    float v1 = lane_xor<1>(S_);
    float S1 = S_ + v1, d1 = S_ - v1;
    float z7 = (l4 & 1) ? -d1 : d1;
    z7 += lane_xor<2>(z7); z7 += fold4(z7); z7 += lane_xor<8>(z7);
    float v2s = lane_xor<2>(S1);
    float S12 = S1 + v2s, d2 = S1 - v2s;
    float z6 = (l4 & 2) ? -d2 : d2;
    z6 += fold4(z6); z6 += lane_xor<8>(z6);
    float v4 = fold4(S12);
    float S124 = S12 + v4, d4 = S12 - v4;
    float z5 = (l4 & 4) ? -d4 : d4;
    z5 += lane_xor<8>(z5);
    float v8 = lane_xor<8>(S124);
    float d8 = S124 - v8;
    float z4 = (l4 & 8) ? -d8 : d8;

    // ---- cross-gate z broadcast via readlane (no LDS, no barrier)
    float acgA[4], acgB[4];
    #pragma unroll
    for (int gg = 0; gg < 4; gg++) {
      const int base = gg * 16;
      float zz0 = rdlane(z0, base), zz1 = rdlane(z1, base);
      float zz2 = rdlane(z2, base), zz3 = rdlane(z3, base);
      float zz4 = rdlane(z4, base), zz5 = rdlane(z5, base);
      float zz6 = rdlane(z6, base), zz7 = rdlane(z7, base);
      float aA = gba[gg], aB = gbb[gg];
      aA = fmaf(zz0, gwa[gg][0], aA); aB = fmaf(zz0, gwb[gg][0], aB);
      aA = fmaf(zz1, gwa[gg][1], aA); aB = fmaf(zz1, gwb[gg][1], aB);
      aA = fmaf(zz2, gwa[gg][2], aA); aB = fmaf(zz2, gwb[gg][2], aB);
      aA = fmaf(zz3, gwa[gg][3], aA); aB = fmaf(zz3, gwb[gg][3], aB);
      aA = fmaf(zz4, gwa[gg][4], aA); aB = fmaf(zz4, gwb[gg][4], aB);
      aA = fmaf(zz5, gwa[gg][5], aA); aB = fmaf(zz5, gwb[gg][5], aB);
      aA = fmaf(zz6, gwa[gg][6], aA); aB = fmaf(zz6, gwb[gg][6], aB);
      aA = fmaf(zz7, gwa[gg][7], aA); aB = fmaf(zz7, gwb[gg][7], aB);
      acgA[gg] = aA; acgB[gg] = aB;
    }
    float it0 = sigm_(acgA[0]), ft0 = sigm_(acgA[1]), gt0 = tanh_(acgA[2]), ot0 = sigm_(acgA[3]);
    float it1 = sigm_(acgB[0]), ft1 = sigm_(acgB[1]), gt1 = tanh_(acgB[2]), ot1 = sigm_(acgB[3]);
    c0 = ft0 * c0 + it0 * gt0;
    c1 = ft1 * c1 + it1 * gt1;
    h0 = ot0 * tanh_(c0);
    h1 = ot1 * tanh_(c1);

    // ---- fused output epilogue (in-wave sums)
    {
      float y0 = h0 + e0, y1 = h1 + e1;
      float r0 = wave_sum(y0 + y1);
      float r1 = wave_sum(y0*y0 + y1*y1);
      float r2 = wave_sum(y0*a0_ + y1*a1_);
      float mn2 = r0 * 0.0078125f;
      float vr2 = fmaf(r1, 0.0078125f, -mn2 * mn2);
      float inv2 = fast_rsq(vr2 + 1e-5f);
      if (L == 0) out[b * Tv + t] = fmaf(inv2, r2 - mn2 * SW, KB);
    }

    // ---- embedding for t+1 (in-wave LN)
    {
      v2 ac0 = XN[0]*EW0[0]; ac0 = pkfma(XN[1],EW0[1],ac0); ac0 = pkfma(XN[2],EW0[2],ac0); ac0 = pkfma(XN[3],EW0[3],ac0);
      v2 ac1 = XN[0]*EW1[0]; ac1 = pkfma(XN[1],EW1[1],ac1); ac1 = pkfma(XN[2],EW1[2],ac1); ac1 = pkfma(XN[3],EW1[3],ac1);
      float er0 = ebb0 + ac0.x + ac0.y;
      float er1 = ebb1 + ac1.x + ac1.y;
      float s1 = wave_sum(er0 + er1);
      float s2 = wave_sum(er0*er0 + er1*er1);
      float mn = s1 * 0.0078125f;
      float vr = fmaf(s2, 0.0078125f, -mn * mn);
      float inv = fast_rsq(vr + 1e-5f);
      e0 = (er0 - mn) * inv * egg0 + ebt0 + pen0;
      e1 = (er1 - mn) * inv * egg1 + ebt1 + pen1;
    }
  }
}

extern "C" void kernel_launch(void* const* d_in, const int* in_sizes, int n_in,
                              void* d_out, int out_size, void* d_ws, size_t ws_size,
                              hipStream_t stream) {
  qlstm_kernel<<<dim3(1024), dim3(64), 0, stream>>>(
      (const float*)d_in[0],  (const float*)d_in[1],  (const float*)d_in[2],  (const float*)d_in[3],
      (const float*)d_in[4],  (const float*)d_in[5],  (const float*)d_in[6],  (const float*)d_in[7],
      (const float*)d_in[8],  (const float*)d_in[9],  (const float*)d_in[10], (const float*)d_in[11],
      (const float*)d_in[12], (const float*)d_in[13], (const float*)d_in[14], (const float*)d_in[15],
      (const float*)d_in[16], (const float*)d_in[17], (const float*)d_in[18], (const float*)d_in[19],
      (const float*)d_in[20], (const float*)d_in[21], (const float*)d_in[22], (const float*)d_in[23],
      (const float*)d_in[24], (const float*)d_in[25],
      (float*)d_out);
}

// Round 11
// 664.800 us; speedup vs baseline: 1.2518x; 1.0137x over previous
//
#include <hip/hip_runtime.h>

#define Tv 128

typedef float v2 __attribute__((ext_vector_type(2)));

__device__ __forceinline__ v2 pkfma(v2 a, v2 b, v2 c) {
  return __builtin_elementwise_fma(a, b, c);
}

// ---- DPP / cross-lane helpers
template<int CTRL>
__device__ __forceinline__ float dppx(float x) {
  return __int_as_float(__builtin_amdgcn_update_dpp(0, __float_as_int(x), CTRL, 0xF, 0xF, true));
}
__device__ __forceinline__ float dpp_rm(float x, int ctrl, int rm) {
  switch (ctrl) {
    default: return 0.f;
    case 0x111: return __int_as_float(__builtin_amdgcn_update_dpp(0, __float_as_int(x), 0x111, 0xF, 0xF, true));
    case 0x112: return __int_as_float(__builtin_amdgcn_update_dpp(0, __float_as_int(x), 0x112, 0xF, 0xF, true));
    case 0x114: return __int_as_float(__builtin_amdgcn_update_dpp(0, __float_as_int(x), 0x114, 0xF, 0xF, true));
    case 0x118: return __int_as_float(__builtin_amdgcn_update_dpp(0, __float_as_int(x), 0x118, 0xF, 0xF, true));
    case 0x142: return __int_as_float(__builtin_amdgcn_update_dpp(0, __float_as_int(x), 0x142, 0xA, 0xF, true));
    case 0x143: return __int_as_float(__builtin_amdgcn_update_dpp(0, __float_as_int(x), 0x143, 0xC, 0xF, true));
  }
}
// full-wave64 sum, broadcast via readlane(63)
__device__ __forceinline__ float wave_sum(float x) {
  x += dpp_rm(x, 0x111, 0xF);
  x += dpp_rm(x, 0x112, 0xF);
  x += dpp_rm(x, 0x114, 0xF);
  x += dpp_rm(x, 0x118, 0xF);
  x += dpp_rm(x, 0x142, 0xA);
  x += dpp_rm(x, 0x143, 0xC);
  return __int_as_float(__builtin_amdgcn_readlane(__float_as_int(x), 63));
}
template<int M>
__device__ __forceinline__ float lane_xor(float x) {
  if constexpr (M == 1)       return dppx<0xB1>(x);    // quad_perm [1,0,3,2]
  else if constexpr (M == 2)  return dppx<0x4E>(x);    // quad_perm [2,3,0,1]
  else if constexpr (M == 8)  return dppx<0x128>(x);   // row_ror:8 == xor8 in 16-row
  else if constexpr (M == 32) return __shfl_xor(x, 32, 64);
  else return __int_as_float(__builtin_amdgcn_ds_swizzle(__float_as_int(x), (M << 10) | 0x1F));
}
// GENERAL xor4 in pure DPP: l^4 = xor1(xor2(mirror)): 7^2^1 = 4
__device__ __forceinline__ float xor4d(float x) {
  return dppx<0xB1>(dppx<0x4E>(dppx<0x141>(x)));
}
// xor4 substitute valid only when x constant over lane bits 0,1 (single mirror)
__device__ __forceinline__ float fold4(float x) { return dppx<0x141>(x); }
__device__ __forceinline__ float bperm(int addr, float x) {
  return __int_as_float(__builtin_amdgcn_ds_bpermute(addr, __float_as_int(x)));
}
__device__ __forceinline__ float rdlane(float x, int l) {
  return __int_as_float(__builtin_amdgcn_readlane(__float_as_int(x), l));
}
__device__ __forceinline__ float fast_rcp(float x){ return __builtin_amdgcn_rcpf(x); }
__device__ __forceinline__ float fast_rsq(float x){ return __builtin_amdgcn_rsqf(x); }
__device__ __forceinline__ float tanh_(float x){
  float e = __expf(2.0f * x);
  return 1.0f - 2.0f * fast_rcp(e + 1.0f);
}
__device__ __forceinline__ float sigm_(float x){
  return fast_rcp(1.0f + __expf(-x));
}

// State: 256 amps = 16 regs x 16 lanes (4 gates across the wave), packed v2 S[8].
// idx bits: b7 b6 b5 (reg k) | b4 (slot x/y) | b3..b0 (lane4). Qubit q <-> bit (7-q):
// q0->b7 (S[k]<->S[k+4]); q1->b6 (k<->k+2); q2->b5 (k<->k+1); q3->b4 (x/y);
// q4..q7 -> lane masks 8,4,2,1 (all handled in DPP).
template<int Q>
__device__ __forceinline__ void ry16(v2* S, float cc, float ss, int l4) {
  const v2 cc2 = {cc, cc};
  if constexpr (Q == 0) {
    const v2 ss2 = {ss, ss};
    #pragma unroll
    for (int k = 0; k < 4; k++) {
      v2 a0 = S[k], a1 = S[k + 4];
      S[k]     = pkfma(cc2, a0, -(ss2 * a1));
      S[k + 4] = pkfma(ss2, a0,  (cc2 * a1));
    }
  } else if constexpr (Q == 1) {
    const v2 ss2 = {ss, ss};
    #pragma unroll
    for (int k0 = 0; k0 < 8; k0 += 4)
      #pragma unroll
      for (int k = k0; k < k0 + 2; k++) {
        v2 a0 = S[k], a1 = S[k + 2];
        S[k]     = pkfma(cc2, a0, -(ss2 * a1));
        S[k + 2] = pkfma(ss2, a0,  (cc2 * a1));
      }
  } else if constexpr (Q == 2) {
    const v2 ss2 = {ss, ss};
    #pragma unroll
    for (int k = 0; k < 8; k += 2) {
      v2 a0 = S[k], a1 = S[k + 1];
      S[k]     = pkfma(cc2, a0, -(ss2 * a1));
      S[k + 1] = pkfma(ss2, a0,  (cc2 * a1));
    }
  }
}

__global__ __launch_bounds__(64, 1) void qlstm_kernel(
    const float* __restrict__ x,     const float* __restrict__ pe,
    const float* __restrict__ emb_w, const float* __restrict__ emb_b,
    const float* __restrict__ emb_g, const float* __restrict__ emb_bt,
    const float* __restrict__ ip_w,  const float* __restrict__ ip_b,
    const float* __restrict__ in_g,  const float* __restrict__ in_b,
    const float* __restrict__ wq_i,  const float* __restrict__ wq_f,
    const float* __restrict__ wq_gt, const float* __restrict__ wq_o,
    const float* __restrict__ pi_w,  const float* __restrict__ pi_b,
    const float* __restrict__ pf_w,  const float* __restrict__ pf_b,
    const float* __restrict__ pg_w,  const float* __restrict__ pg_b,
    const float* __restrict__ po_w,  const float* __restrict__ po_b,
    const float* __restrict__ on_g,  const float* __restrict__ on_b,
    const float* __restrict__ out_w, const float* __restrict__ out_b,
    float* __restrict__ out)
{
  __shared__ float cs[4][68];   // per gate, per layer: 16 floats (8 x (cos,sin))
  const int L   = threadIdx.x;  // 0..63
  const int b   = blockIdx.x;
  const int l4  = L & 15;
  const int gate = L >> 4;
  const int o8  = L & 7;

  #pragma unroll
  for (int half = 0; half < 2; half++) {
    int e = L + half * 64;
    int gg = e >> 5, rem = e & 31;
    const float* wsel = (gg == 0) ? wq_i : (gg == 1) ? wq_f : (gg == 2) ? wq_gt : wq_o;
    float th = wsel[rem] * 0.5f;
    cs[gg][(rem >> 3) * 16 + (rem & 7) * 2]     = __cosf(th);
    cs[gg][(rem >> 3) * 16 + (rem & 7) * 2 + 1] = __sinf(th);
  }
  __syncthreads();

  // ---- per-lane rows j0 = L, j1 = L+64
  const int j0 = L, j1 = L + 64;
  v2 EW0[4], EW1[4];
  {
    float4 a = *reinterpret_cast<const float4*>(emb_w + j0 * 8);
    float4 c = *reinterpret_cast<const float4*>(emb_w + j0 * 8 + 4);
    EW0[0] = {a.x,a.y}; EW0[1] = {a.z,a.w}; EW0[2] = {c.x,c.y}; EW0[3] = {c.z,c.w};
    float4 d = *reinterpret_cast<const float4*>(emb_w + j1 * 8);
    float4 f = *reinterpret_cast<const float4*>(emb_w + j1 * 8 + 4);
    EW1[0] = {d.x,d.y}; EW1[1] = {d.z,d.w}; EW1[2] = {f.x,f.y}; EW1[3] = {f.z,f.w};
  }
  float ebb0 = emb_b[j0], egg0 = emb_g[j0], ebt0 = emb_bt[j0];
  float ebb1 = emb_b[j1], egg1 = emb_g[j1], ebt1 = emb_bt[j1];
  v2 IPW1a[4], IPW2a[4], IPW1b[4], IPW2b[4];
  #pragma unroll
  for (int k = 0; k < 4; k++) {
    IPW1a[k] = {ip_w[(2*k)*256 + j0],       ip_w[(2*k+1)*256 + j0]};
    IPW2a[k] = {ip_w[(2*k)*256 + 128 + j0], ip_w[(2*k+1)*256 + 128 + j0]};
    IPW1b[k] = {ip_w[(2*k)*256 + j1],       ip_w[(2*k+1)*256 + j1]};
    IPW2b[k] = {ip_w[(2*k)*256 + 128 + j1], ip_w[(2*k+1)*256 + 128 + j1]};
  }
  float gwa[4][8], gwb[4][8], gba[4], gbb[4];
  #pragma unroll
  for (int gg = 0; gg < 4; gg++) {
    const float* pw = (gg == 0) ? pi_w : (gg == 1) ? pf_w : (gg == 2) ? pg_w : po_w;
    const float* pb = (gg == 0) ? pi_b : (gg == 1) ? pf_b : (gg == 2) ? pg_b : po_b;
    float4 a = *reinterpret_cast<const float4*>(pw + j0 * 8);
    float4 c = *reinterpret_cast<const float4*>(pw + j0 * 8 + 4);
    gwa[gg][0]=a.x; gwa[gg][1]=a.y; gwa[gg][2]=a.z; gwa[gg][3]=a.w;
    gwa[gg][4]=c.x; gwa[gg][5]=c.y; gwa[gg][6]=c.z; gwa[gg][7]=c.w;
    float4 d = *reinterpret_cast<const float4*>(pw + j1 * 8);
    float4 f = *reinterpret_cast<const float4*>(pw + j1 * 8 + 4);
    gwb[gg][0]=d.x; gwb[gg][1]=d.y; gwb[gg][2]=d.z; gwb[gg][3]=d.w;
    gwb[gg][4]=f.x; gwb[gg][5]=f.y; gwb[gg][6]=f.z; gwb[gg][7]=f.w;
    gba[gg] = pb[j0]; gbb[gg] = pb[j1];
  }
  float a0_ = on_g[j0] * out_w[j0], a1_ = on_g[j1] * out_w[j1];
  float bw0 = on_b[j0] * out_w[j0], bw1 = on_b[j1] * out_w[j1];
  float ipb0 = ip_b[o8], ing = in_g[o8], inb = in_b[o8];

  // composed-CNOT bpermute addresses (one round per layer, R10-verified)
  const int grp = L & 48;
  int aX, aY;
  {
    int lx = l4 ^ ((l4 & 8) ? 4 : 0) ^ ((l4 & 4) ? 2 : 0) ^ ((((l4 >> 1) ^ (l4 >> 2)) & 1) ? 1 : 0);
    aX = (grp | lx) << 2;
    aY = aX ^ 48;
  }
  const int a32 = (L ^ 32) << 2, a48 = (L ^ 48) << 2;

  const float* xbase = x + (size_t)b * Tv * 8;
  float h0 = 0.f, h1 = 0.f, c0 = 0.f, c1 = 0.f;

  float e0, e1;
  const float SW = wave_sum(a0_ + a1_);
  const float KB = wave_sum(bw0 + bw1) + out_b[0];
  {
    float4 a = *reinterpret_cast<const float4*>(xbase);
    float4 cq = *reinterpret_cast<const float4*>(xbase + 4);
    v2 XT[4] = {{a.x,a.y},{a.z,a.w},{cq.x,cq.y},{cq.z,cq.w}};
    v2 ac0 = XT[0]*EW0[0]; ac0 = pkfma(XT[1],EW0[1],ac0); ac0 = pkfma(XT[2],EW0[2],ac0); ac0 = pkfma(XT[3],EW0[3],ac0);
    v2 ac1 = XT[0]*EW1[0]; ac1 = pkfma(XT[1],EW1[1],ac1); ac1 = pkfma(XT[2],EW1[2],ac1); ac1 = pkfma(XT[3],EW1[3],ac1);
    float er0 = ebb0 + ac0.x + ac0.y;
    float er1 = ebb1 + ac1.x + ac1.y;
    float s1 = wave_sum(er0 + er1);
    float s2 = wave_sum(er0*er0 + er1*er1);
    float mn = s1 * 0.0078125f;
    float vr = fmaf(s2, 0.0078125f, -mn * mn);
    float inv = fast_rsq(vr + 1e-5f);
    e0 = (er0 - mn) * inv * egg0 + ebt0 + pe[j0];
    e1 = (er1 - mn) * inv * egg1 + ebt1 + pe[j1];
  }

  #pragma unroll 1
  for (int t = 0; t < Tv; t++) {
    // ---- prefetch next x, pe
    v2 XN[4]; float pen0, pen1;
    {
      int tn = (t + 1) & (Tv - 1);
      float4 a = *reinterpret_cast<const float4*>(xbase + tn * 8);
      float4 cq = *reinterpret_cast<const float4*>(xbase + tn * 8 + 4);
      XN[0] = {a.x,a.y}; XN[1] = {a.z,a.w}; XN[2] = {cq.x,cq.y}; XN[3] = {cq.z,cq.w};
      pen0 = pe[tn * 128 + j0];
      pen1 = pe[tn * 128 + j1];
    }

    // ---- proj butterfly: m1,m2 (DPP), m4 (3-DPP), m8 (DPP), cross-row (1 DS round)
    const v2 e20 = {e0,e0}, h20 = {h0,h0}, e21 = {e1,e1}, h21 = {h1,h1};
    v2 P2[4];
    #pragma unroll
    for (int k = 0; k < 4; k++) {
      v2 acc = e20 * IPW1a[k];
      acc = pkfma(h20, IPW2a[k], acc);
      acc = pkfma(e21, IPW1b[k], acc);
      P2[k] = pkfma(h21, IPW2b[k], acc);
    }
    const int bb0 = L & 1, bb1 = L & 2, bb2 = L & 4;
    float q_[4];
    #pragma unroll
    for (int k = 0; k < 4; k++) {
      float keep = bb0 ? P2[k].y : P2[k].x;
      float send = bb0 ? P2[k].x : P2[k].y;
      q_[k] = keep + lane_xor<1>(send);
    }
    float r_[2];
    #pragma unroll
    for (int k = 0; k < 2; k++) {
      float keep = bb1 ? q_[2*k+1] : q_[2*k];
      float send = bb1 ? q_[2*k]   : q_[2*k+1];
      r_[k] = keep + lane_xor<2>(send);
    }
    float u;
    {
      float keep = bb2 ? r_[1] : r_[0];
      float send = bb2 ? r_[0] : r_[1];
      u = keep + xor4d(send);
    }
    u += lane_xor<8>(u);
    {
      float p16 = lane_xor<16>(u);
      float p32 = bperm(a32, u);
      float p48 = bperm(a48, u);
      u = (u + p16) + (p32 + p48);
    }

    // ---- angles: tanh + LN(8) all-DPP; encode factors via readlane
    float tv = tanh_(u + ipb0);
    float m1 = tv, m2 = tv * tv;
    m1 += lane_xor<1>(m1); m2 += lane_xor<1>(m2);
    m1 += lane_xor<2>(m1); m2 += lane_xor<2>(m2);
    m1 += fold4(m1);       m2 += fold4(m2);
    float pm = m1 * 0.125f;
    float pv = fmaf(m2, 0.125f, -pm * pm);
    float theta = (tv - pm) * fast_rsq(pv + 1e-5f) * ing + inb;
    float ph = theta * 0.5f;
    float cE = __cosf(ph), sE = __sinf(ph);
    float fm = cE - sE, fp = cE + sE;
    float f_[16];
    #pragma unroll
    for (int qq = 0; qq < 8; qq++) {
      f_[2*qq]     = rdlane(fm, qq);
      f_[2*qq + 1] = rdlane(fp, qq);
    }

    // ---- encode
    v2 S[8];
    {
      float lf = f_[8 + ((l4 >> 3) & 1)] * f_[10 + ((l4 >> 2) & 1)]
               * f_[12 + ((l4 >> 1) & 1)] * f_[14 + (l4 & 1)];
      lf *= 0.0625f;
      const v2 F67 = {f_[6], f_[7]};
      #pragma unroll
      for (int k = 0; k < 8; k++) {
        float tk = lf * f_[(k >> 2) & 1] * f_[2 + ((k >> 1) & 1)] * f_[4 + (k & 1)];
        v2 tk2 = {tk, tk};
        S[k] = tk2 * F67;
      }
    }

    // ---- 4 variational layers: bperm burst, then per-k lane-RYs (partial waits),
    //      then reg-RYs. All lane exchanges are DPP (no DS in RYs).
    #pragma unroll
    for (int l = 0; l < 4; l++) {
      const float* cb = &cs[gate][l * 16];
      float4 cA = *reinterpret_cast<const float4*>(cb);
      float4 cB = *reinterpret_cast<const float4*>(cb + 4);
      float4 cC = *reinterpret_cast<const float4*>(cb + 8);
      float4 cD = *reinterpret_cast<const float4*>(cb + 12);
      v2 N[8];
      N[0].x = bperm(aX, S[0].x); N[0].y = bperm(aY, S[0].y);
      N[1].x = bperm(aX, S[1].y); N[1].y = bperm(aY, S[1].x);
      N[2].x = bperm(aX, S[3].y); N[2].y = bperm(aY, S[3].x);
      N[3].x = bperm(aX, S[2].x); N[3].y = bperm(aY, S[2].y);
      N[4].x = bperm(aX, S[6].x); N[4].y = bperm(aY, S[6].y);
      N[5].x = bperm(aX, S[7].y); N[5].y = bperm(aY, S[7].x);
      N[6].x = bperm(aX, S[5].y); N[6].y = bperm(aY, S[5].x);
      N[7].x = bperm(aX, S[4].x); N[7].y = bperm(aY, S[4].y);
      // per-layer lane-RY coefficients
      const v2 c3v = {cB.z, cB.z};
      const v2 nss3 = {-cB.w, cB.w};
      float sg4 = (l4 & 8) ? cC.y : -cC.y;  const v2 c4v = {cC.x, cC.x}, sg4v = {sg4, sg4};
      float sg5 = (l4 & 4) ? cC.w : -cC.w;  const v2 c5v = {cC.z, cC.z}, sg5v = {sg5, sg5};
      float sg6 = (l4 & 2) ? cD.y : -cD.y;  const v2 c6v = {cD.x, cD.x}, sg6v = {sg6, sg6};
      float sg7 = (l4 & 1) ? cD.w : -cD.w;  const v2 c7v = {cD.z, cD.z}, sg7v = {sg7, sg7};
      #pragma unroll
      for (int k = 0; k < 8; k++) {
        v2 s = N[k];
        { v2 sw = __builtin_shufflevector(s, s, 1, 0);                       // q3
          s = pkfma(c3v, s, nss3 * sw); }
        { v2 o; o.x = lane_xor<8>(s.x); o.y = lane_xor<8>(s.y);              // q4
          s = pkfma(c4v, s, sg4v * o); }
        { v2 o; o.x = xor4d(s.x); o.y = xor4d(s.y);                          // q5
          s = pkfma(c5v, s, sg5v * o); }
        { v2 o; o.x = lane_xor<2>(s.x); o.y = lane_xor<2>(s.y);              // q6
          s = pkfma(c6v, s, sg6v * o); }
        { v2 o; o.x = lane_xor<1>(s.x); o.y = lane_xor<1>(s.y);              // q7
          s = pkfma(c7v, s, sg7v * o); }
        S[k] = s;
      }
      ry16<0>(S, cA.x, cA.y, l4);
      ry16<1>(S, cA.z, cA.w, l4);
      ry16<2>(S, cB.x, cB.y, l4);
    }

    // ---- measure: reg-qubit combos + all-DPP lane trees (zero DS)
    v2 P[8];
    #pragma unroll
    for (int k = 0; k < 8; k++) P[k] = S[k] * S[k];
    v2 Q01 = P[0] + P[1], Q23 = P[2] + P[3], Q45 = P[4] + P[5], Q67 = P[6] + P[7];
    v2 Slo = Q01 + Q23, Shi = Q45 + Q67;
    float z0 = (Slo.x + Slo.y) - (Shi.x + Shi.y);
    v2 T1p = Q01 + Q45, T1m = Q23 + Q67;
    float z1 = (T1p.x + T1p.y) - (T1m.x + T1m.y);
    v2 T2p = (P[0] + P[2]) + (P[4] + P[6]);
    v2 T2m = (P[1] + P[3]) + (P[5] + P[7]);
    float z2 = (T2p.x + T2p.y) - (T2m.x + T2m.y);
    v2 G = Slo + Shi;
    float z3 = G.x - G.y;
    float S_ = G.x + G.y;
    z0 += lane_xor<1>(z0); z1 += lane_xor<1>(z1); z2 += lane_xor<1>(z2); z3 += lane_xor<1>(z3);
    z0 += lane_xor<2>(z0); z1 += lane_xor<2>(z1); z2 += lane_xor<2>(z2); z3 += lane_xor<2>(z3);
    z0 += fold4(z0);       z1 += fold4(z1);       z2 += fold4(z2);       z3 += fold4(z3);
    z0 += lane_xor<8>(z0); z1 += lane_xor<8>(z1); z2 += lane_xor<8>(z2); z3 += lane_xor<8>(z3);
    float v1 = lane_xor<1>(S_);
    float S1 = S_ + v1, d1 = S_ - v1;
    float z7 = (l4 & 1) ? -d1 : d1;
    z7 += lane_xor<2>(z7); z7 += fold4(z7); z7 += lane_xor<8>(z7);
    float v2s = lane_xor<2>(S1);
    float S12 = S1 + v2s, d2 = S1 - v2s;
    float z6 = (l4 & 2) ? -d2 : d2;
    z6 += fold4(z6); z6 += lane_xor<8>(z6);
    float v4 = fold4(S12);
    float S124 = S12 + v4, d4 = S12 - v4;
    float z5 = (l4 & 4) ? -d4 : d4;
    z5 += lane_xor<8>(z5);
    float v8 = lane_xor<8>(S124);
    float d8 = S124 - v8;
    float z4 = (l4 & 8) ? -d8 : d8;

    // ---- cross-gate z broadcast via readlane
    float acgA[4], acgB[4];
    #pragma unroll
    for (int gg = 0; gg < 4; gg++) {
      const int base = gg * 16;
      float zz0 = rdlane(z0, base), zz1 = rdlane(z1, base);
      float zz2 = rdlane(z2, base), zz3 = rdlane(z3, base);
      float zz4 = rdlane(z4, base), zz5 = rdlane(z5, base);
      float zz6 = rdlane(z6, base), zz7 = rdlane(z7, base);
      float aA = gba[gg], aB = gbb[gg];
      aA = fmaf(zz0, gwa[gg][0], aA); aB = fmaf(zz0, gwb[gg][0], aB);
      aA = fmaf(zz1, gwa[gg][1], aA); aB = fmaf(zz1, gwb[gg][1], aB);
      aA = fmaf(zz2, gwa[gg][2], aA); aB = fmaf(zz2, gwb[gg][2], aB);
      aA = fmaf(zz3, gwa[gg][3], aA); aB = fmaf(zz3, gwb[gg][3], aB);
      aA = fmaf(zz4, gwa[gg][4], aA); aB = fmaf(zz4, gwb[gg][4], aB);
      aA = fmaf(zz5, gwa[gg][5], aA); aB = fmaf(zz5, gwb[gg][5], aB);
      aA = fmaf(zz6, gwa[gg][6], aA); aB = fmaf(zz6, gwb[gg][6], aB);
      aA = fmaf(zz7, gwa[gg][7], aA); aB = fmaf(zz7, gwb[gg][7], aB);
      acgA[gg] = aA; acgB[gg] = aB;
    }
    float it0 = sigm_(acgA[0]), ft0 = sigm_(acgA[1]), gt0 = tanh_(acgA[2]), ot0 = sigm_(acgA[3]);
    float it1 = sigm_(acgB[0]), ft1 = sigm_(acgB[1]), gt1 = tanh_(acgB[2]), ot1 = sigm_(acgB[3]);
    c0 = ft0 * c0 + it0 * gt0;
    c1 = ft1 * c1 + it1 * gt1;
    h0 = ot0 * tanh_(c0);
    h1 = ot1 * tanh_(c1);

    // ---- fused output epilogue
    {
      float y0 = h0 + e0, y1 = h1 + e1;
      float r0 = wave_sum(y0 + y1);
      float r1 = wave_sum(y0*y0 + y1*y1);
      float r2 = wave_sum(y0*a0_ + y1*a1_);
      float mn2 = r0 * 0.0078125f;
      float vr2 = fmaf(r1, 0.0078125f, -mn2 * mn2);
      float inv2 = fast_rsq(vr2 + 1e-5f);
      if (L == 0) out[b * Tv + t] = fmaf(inv2, r2 - mn2 * SW, KB);
    }

    // ---- embedding for t+1
    {
      v2 ac0 = XN[0]*EW0[0]; ac0 = pkfma(XN[1],EW0[1],ac0); ac0 = pkfma(XN[2],EW0[2],ac0); ac0 = pkfma(XN[3],EW0[3],ac0);
      v2 ac1 = XN[0]*EW1[0]; ac1 = pkfma(XN[1],EW1[1],ac1); ac1 = pkfma(XN[2],EW1[2],ac1); ac1 = pkfma(XN[3],EW1[3],ac1);
      float er0 = ebb0 + ac0.x + ac0.y;
      float er1 = ebb1 + ac1.x + ac1.y;
      float s1 = wave_sum(er0 + er1);
      float s2 = wave_sum(er0*er0 + er1*er1);
      float mn = s1 * 0.0078125f;
      float vr = fmaf(s2, 0.0078125f, -mn * mn);
      float inv = fast_rsq(vr + 1e-5f);
      e0 = (er0 - mn) * inv * egg0 + ebt0 + pen0;
      e1 = (er1 - mn) * inv * egg1 + ebt1 + pen1;
    }
  }
}

extern "C" void kernel_launch(void* const* d_in, const int* in_sizes, int n_in,
                              void* d_out, int out_size, void* d_ws, size_t ws_size,
                              hipStream_t stream) {
  qlstm_kernel<<<dim3(1024), dim3(64), 0, stream>>>(
      (const float*)d_in[0],  (const float*)d_in[1],  (const float*)d_in[2],  (const float*)d_in[3],
      (const float*)d_in[4],  (const float*)d_in[5],  (const float*)d_in[6],  (const float*)d_in[7],
      (const float*)d_in[8],  (const float*)d_in[9],  (const float*)d_in[10], (const float*)d_in[11],
      (const float*)d_in[12], (const float*)d_in[13], (const float*)d_in[14], (const float*)d_in[15],
      (const float*)d_in[16], (const float*)d_in[17], (const float*)d_in[18], (const float*)d_in[19],
      (const float*)d_in[20], (const float*)d_in[21], (const float*)d_in[22], (const float*)d_in[23],
      (const float*)d_in[24], (const float*)d_in[25],
      (float*)d_out);
}